// Round 2
// baseline (455.336 us; speedup 1.0000x reference)
//
#include <hip/hip_runtime.h>
#include <hip/hip_bf16.h>

typedef short bf16x8 __attribute__((ext_vector_type(8)));
typedef float f32x4 __attribute__((ext_vector_type(4)));

constexpr int C_IN = 64, H_IN = 128, W_IN = 128, C_OUT = 128, OH = 126, OW = 126;
constexpr int XPAD = 72;      // Xs row stride in bf16 (144 B: 16B-aligned, frag reads conflict-free)
constexpr float SUBC = 0.7f;  // SUB1 + SUB2

// Reorder conv weights OIHW fp32 -> wr2[k9][half][jt][lane][jj] bf16:
// each 64-lane x 16B run is exactly one B-fragment (perfectly coalesced global frag loads).
__global__ void reorder_weights(const float* __restrict__ w, __hip_bfloat16* __restrict__ wr2) {
    int o = blockIdx.x * 256 + threadIdx.x;
    if (o >= 9 * 2 * 8 * 64 * 8) return;
    int jj   = o & 7;
    int lane = (o >> 3) & 63;
    int jt   = (o >> 9) & 7;
    int half = (o >> 12) & 1;
    int k9   = o >> 13;
    int co = jt * 16 + (lane & 15);
    int ci = half * 32 + (lane >> 4) * 8 + jj;
    int kh = k9 / 3, kw = k9 % 3;
    wr2[o] = __float2bfloat16(w[((co * C_IN + ci) * 3 + kh) * 3 + kw]);
}

// One block per (n, oh): implicit GEMM, M=128 (ow pad 126), N=128 (co), K=576
// A (x) staged in LDS via in-register transpose; B (weights) loaded straight from L2-resident wr2.
__global__ __launch_bounds__(256, 3) void conv_mish(
    const float* __restrict__ x, const __hip_bfloat16* __restrict__ wr2,
    const float* __restrict__ bias, float* __restrict__ out)
{
    __shared__ __hip_bfloat16 Xs[128 * XPAD];   // [w][ci], 18432 B

    int b  = blockIdx.x;
    int lb = (b & 7) * 504 + (b >> 3);          // XCD swizzle: 4032 = 8 * 504
    int n  = lb / OH;
    int oh = lb % OH;

    int tid  = threadIdx.x;
    int lane = tid & 63;
    int wv   = tid >> 6;
    int wm   = wv >> 1;
    int wn   = wv & 1;
    int quad = lane >> 4;
    int l16  = lane & 15;

    f32x4 acc[4][4] = {};

    const float* xn = x + (size_t)n * C_IN * H_IN * W_IN;

    for (int kh = 0; kh < 3; ++kh) {
        __syncthreads();   // previous kh's Xs readers done
        // ---- stage Xs[w][ci]: 16 coalesced float2 loads, register transpose, 4x ds_write_b128 ----
        {
            int h  = oh + kh;
            int cB = wv;   // ci-block 0..3 (16 ci each)
            const float2* src = (const float2*)(xn + ((size_t)(cB * 16) * H_IN + h) * W_IN) + lane;
            float2 ld[16];
            #pragma unroll
            for (int j = 0; j < 16; ++j) ld[j] = src[(size_t)j * (H_IN * W_IN / 2)];
            #pragma unroll
            for (int sw = 0; sw < 2; ++sw) {
                #pragma unroll
                for (int sc = 0; sc < 2; ++sc) {
                    bf16x8 v;
                    #pragma unroll
                    for (int jj = 0; jj < 8; ++jj) {
                        float f = sw ? ld[sc * 8 + jj].y : ld[sc * 8 + jj].x;
                        __hip_bfloat16 hbf = __float2bfloat16(f);
                        v[jj] = *(short*)&hbf;
                    }
                    // w = 2*lane+sw -> banks (8*lane+..)%32: worst 2-way, ~free
                    *(bf16x8*)&Xs[(2 * lane + sw) * XPAD + (2 * cB + sc) * 8] = v;
                }
            }
        }
        __syncthreads();   // Xs visible
        #pragma unroll 1
        for (int kw = 0; kw < 3; ++kw) {
            const __hip_bfloat16* wb = wr2 + (size_t)(kh * 3 + kw) * 8192;
            #pragma unroll
            for (int half = 0; half < 2; ++half) {
                int k0 = half * 32 + quad * 8;
                bf16x8 a[4], bw[4];
                #pragma unroll
                for (int j = 0; j < 4; ++j) {
                    int jt = wn * 4 + j;
                    bw[j] = *(const bf16x8*)(wb + ((half * 8 + jt) * 64 + lane) * 8);
                }
                #pragma unroll
                for (int i = 0; i < 4; ++i) {
                    int m = wm * 64 + i * 16 + l16;
                    int widx = m + kw; if (widx > 127) widx = 127;  // pad rows never stored
                    a[i] = *(const bf16x8*)&Xs[widx * XPAD + k0];
                }
                #pragma unroll
                for (int i = 0; i < 4; ++i)
                    #pragma unroll
                    for (int j = 0; j < 4; ++j)
                        acc[i][j] = __builtin_amdgcn_mfma_f32_16x16x32_bf16(a[i], bw[j], acc[i][j], 0, 0, 0);
            }
        }
    }

    // ---- epilogue: bias - 0.7, Mish = v * t/(t+2), t = e*(e+2), e = exp(v) ----
    for (int j = 0; j < 4; ++j) {
        int co = wn * 64 + j * 16 + l16;
        float bb = bias[co] - SUBC;
        for (int i = 0; i < 4; ++i) {
            int ow0 = wm * 64 + i * 16 + quad * 4;   // <= 124
            float o[4];
            for (int r = 0; r < 4; ++r) {
                float v = acc[i][j][r] + bb;
                float e = __expf(v);
                float t = e * (e + 2.0f);
                float m = v * t * __builtin_amdgcn_rcpf(t + 2.0f);
                o[r] = (v > 20.0f) ? v : m;
            }
            float* dst = out + (((size_t)n * C_OUT + co) * OH + oh) * OW + ow0;
            float2 p0; p0.x = o[0]; p0.y = o[1];
            *(float2*)dst = p0;
            if (ow0 + 2 < OW) {
                float2 p1; p1.x = o[2]; p1.y = o[3];
                *(float2*)(dst + 2) = p1;
            }
        }
    }
}

extern "C" void kernel_launch(void* const* d_in, const int* in_sizes, int n_in,
                              void* d_out, int out_size, void* d_ws, size_t ws_size,
                              hipStream_t stream) {
    const float* x    = (const float*)d_in[0];
    const float* w    = (const float*)d_in[1];
    const float* bias = (const float*)d_in[2];
    float* out        = (float*)d_out;
    __hip_bfloat16* wr2 = (__hip_bfloat16*)d_ws;   // 73728 bf16 = 147456 B

    reorder_weights<<<(73728 + 255) / 256, 256, 0, stream>>>(w, wr2);
    conv_mish<<<32 * OH, 256, 0, stream>>>(x, wr2, bias, out);
}